// Round 19
// baseline (45.297 us; speedup 1.0000x reference)
//
#include <hip/hip_runtime.h>
#include <hip/hip_bf16.h>

// Problem: B=16,H=16,P=128,D=128,NF=12
// rows per branch = B*H*P = 32768; total rows (q then k) = 65536.
//
// R19 = R18 with the sin-dot's coef reads moved OFF the LDS pipe:
//   R18 read cfl[u*128+d] from LDS inside the inner loop = 192 ds_read_b32
//   per wave (~15 us/CU of LDS-pipe time — the real phase-2 limiter).
//   R19 hoists cf[4][12] into registers (R17's thread map: 4 cols x 4 rows
//   within the wave's 16x64 region) and computes ONE row's sin-dot per
//   s-iter, co-scheduled with the MFMA. Phase-2 LDS = 16 b128 MFMA reads.
//   cf dies before the barrier; acc[16]+fv[16] cross it (static).
// k_attn: grid 256 (one bh per block) — w_qk traffic halved.
//
// ws layout (floats): sums_lo [0,65536)  sums_hi [65536,131072)
//                     wbf: ushort[16384] at float offset 131072

typedef float          f32x4 __attribute__((ext_vector_type(4)));
typedef short          s16x8 __attribute__((ext_vector_type(8)));
typedef int            s32x4 __attribute__((ext_vector_type(4)));
typedef unsigned short u16x8 __attribute__((ext_vector_type(8)));

#define LOG2E   1.44269504f
#define NLOG2E -1.44269504f
#define INV2PI  0.15915494309189535f

static __device__ __forceinline__ float hw_exp2(float x) {   // 2^x
    float r;
    asm("v_exp_f32 %0, %1" : "=v"(r) : "v"(x));
    return r;
}
static __device__ __forceinline__ float hw_fract(float x) {
    float r;
    asm("v_fract_f32 %0, %1" : "=v"(r) : "v"(x));
    return r;
}
static __device__ __forceinline__ float hw_sin01(float f) {  // sin(2*pi*f)
    float r;
    asm("v_sin_f32 %0, %1" : "=v"(r) : "v"(f));
    return r;
}
static __device__ __forceinline__ float hw_cos01(float f) {  // cos(2*pi*f)
    float r;
    asm("v_cos_f32 %0, %1" : "=v"(r) : "v"(f));
    return r;
}
static __device__ __forceinline__ float fastrcp(float x) {
    return __builtin_amdgcn_rcpf(x);
}
static __device__ __forceinline__ unsigned int cvt_pk_bf16(float lo, float hi) {
    unsigned int r;
    asm("v_cvt_pk_bf16_f32 %0, %1, %2" : "=v"(r) : "v"(lo), "v"(hi));
    return r;
}
static __device__ __forceinline__ float sigmoid_fast(float z) {
    return fastrcp(1.f + hw_exp2(z * NLOG2E));
}
// XOR swizzle for [row][256B] bf16 LDS tiles read 16B/lane (measured-good)
static __device__ __forceinline__ int swz(int local) {
    return local ^ (((local >> 8) & 7) << 4);
}

__global__ __launch_bounds__(256) void k_convert(const float* __restrict__ bw,
                                                 unsigned short* __restrict__ wbf) {
    int i = blockIdx.x * 256 + threadIdx.x;
    if (i < 128 * 128) {
        __hip_bfloat16 h = __float2bfloat16(bw[i]);
        unsigned short r;
        __builtin_memcpy(&r, &h, 2);
        wbf[i] = r;
    }
}

__global__ __launch_bounds__(512, 4) void k_branch(
    const float* __restrict__ q, const float* __restrict__ k,
    const unsigned short* __restrict__ wbf,   // W bf16 [d][e]
    const float* __restrict__ gridv,          // [12], == 1..12
    const float* __restrict__ coef_q, const float* __restrict__ coef_k,
    const float* __restrict__ sbase,          // scale_base (1,H,P,D)
    const float* __restrict__ ssp,            // scale_sp   (1,H,P,D)
    float* __restrict__ sums_lo, float* __restrict__ sums_hi)
{
    __shared__ char smem[32768];
    // [0,32768): W bf16 swizzled; after barrier-2: per-wave fv bounce
    // regions ([16][64] f32, rotation swizzle).

    const int t = threadIdx.x;
    const int lane = t & 63, w = t >> 6;      // 8 waves
    const int wr = w >> 1;                    // row group 0..3
    const int ch = w & 1;                     // col half 0/1
    const int r15 = lane & 15, g4 = lane >> 4;
    const int ce = lane & 15;                 // sin-map col quad (0..15)
    const int re = lane >> 4;                 // sin-map row quad (0..3)
    const int row0 = blockIdx.x * 64;
    const bool is_q = row0 < 32768;
    const float* X = is_q ? q : k;
    const float* coef = is_q ? coef_q : coef_k;
    const int xrow0 = is_q ? row0 : row0 - 32768;
    const float g1 = gridv[0];                // == 1.0; freqs are g1*(1..12)
    const float grev = g1 * INV2PI;

    // ---- phase 1: stage W bf16 (4 x 16B per thread, coalesced) ----
    #pragma unroll
    for (int it = 0; it < 4; ++it) {
        int c = it * 512 + t;                 // chunk 0..2047
        u16x8 v = *(const u16x8*)&wbf[c * 8];
        *(u16x8*)(smem + swz(c * 16)) = v;
    }
    __syncthreads();

    // ---- phase 2: MFMA (swapped operands) + co-scheduled sin-dot ----
    // cf hoisted ONCE into registers (dies before the barrier).
    const int gcol = ch * 64 + ce * 4;        // sin-map cols gcol..gcol+3
    float cf[4][12];
    #pragma unroll
    for (int j = 0; j < 4; ++j) {
        const float4* cp = (const float4*)&coef[(gcol + j) * 12];
        float4 c0 = cp[0], c1 = cp[1], c2 = cp[2];
        cf[j][0] = c0.x; cf[j][1] = c0.y; cf[j][2]  = c0.z; cf[j][3]  = c0.w;
        cf[j][4] = c1.x; cf[j][5] = c1.y; cf[j][6]  = c1.z; cf[j][7]  = c1.w;
        cf[j][8] = c2.x; cf[j][9] = c2.y; cf[j][10] = c2.z; cf[j][11] = c2.w;
    }

    const int xrow = wr * 16 + r15;           // MFMA-frag x-row in block
    const float* xrowp = &X[(xrow0 + xrow) * 128];
    const int hp = (row0 + xrow) & 2047;

    f32x4 acc[4];
    #pragma unroll
    for (int n = 0; n < 4; ++n) acc[n] = (f32x4){0.f, 0.f, 0.f, 0.f};
    float fv[16];                             // [s*4+j], one row per s-iter

    #pragma unroll
    for (int s = 0; s < 4; ++s) {
        // MFMA A-operand source: silu(x) fragment for row=xrow
        const float4* xp = (const float4*)&xrowp[s * 32 + g4 * 8];
        float4 x0 = xp[0], x1 = xp[1];
        float xsv[8] = {x0.x, x0.y, x0.z, x0.w, x1.x, x1.y, x1.z, x1.w};
        float sl[8];
        #pragma unroll
        for (int j = 0; j < 8; ++j) {
            float e = hw_exp2(xsv[j] * NLOG2E);          // e^-x
            sl[j] = xsv[j] * fastrcp(1.f + e);           // silu
        }
        s32x4 a4 = {(int)cvt_pk_bf16(sl[0], sl[1]), (int)cvt_pk_bf16(sl[2], sl[3]),
                    (int)cvt_pk_bf16(sl[4], sl[5]), (int)cvt_pk_bf16(sl[6], sl[7])};
        s16x8 af = __builtin_bit_cast(s16x8, a4);

        // sin-dot for ONE row of the sin-map: row = wr*16 + re*4 + s
        {
            int srow = wr * 16 + re * 4 + s;
            int shp = (row0 + srow) & 2047;
            float4 xs4 = *(const float4*)&X[(xrow0 + srow) * 128 + gcol];
            float4 sp4 = *(const float4*)&ssp[shp * 128 + gcol];
            float xq[4]  = {xs4.x, xs4.y, xs4.z, xs4.w};
            float spq[4] = {sp4.x, sp4.y, sp4.z, sp4.w};
            #pragma unroll
            for (int j = 0; j < 4; ++j) {
                float rev = hw_fract(grev * xq[j]);
                float s1 = hw_sin01(rev);
                float cv = hw_cos01(rev);
                float t2 = cv + cv;
                float sprev = 0.f, scur = s1;
                float f = cf[j][0] * s1;
                #pragma unroll
                for (int u = 1; u < 12; ++u) {
                    float sn = __builtin_fmaf(t2, scur, -sprev);
                    f = __builtin_fmaf(cf[j][u], sn, f);
                    sprev = scur; scur = sn;
                }
                fv[s * 4 + j] = f * spq[j];
            }
        }

        #pragma unroll
        for (int n = 0; n < 4; ++n) {
            s16x8 bfw = *(const s16x8*)(smem + swz((ch * 64 + n * 16 + r15) * 256
                                                   + s * 64 + g4 * 16));
            // swapped: A = W-frag (M=d), B = silu-frag (N=x-row)
            acc[n] = __builtin_amdgcn_mfma_f32_16x16x32_bf16(bfw, af, acc[n], 0, 0, 0);
        }
    }
    __syncthreads();                          // all waves done with W region

    // ---- phase 3: fv bounce through dead-W overlay (wave-private, rotated)
    // semantic layout [row 0..15][dloc 0..63], addr = row*64 + ((dloc+row*4)&63)
    float* myfv = (float*)smem + w * 1024;    // [16][64] floats
    #pragma unroll
    for (int s = 0; s < 4; ++s) {
        int rloc = re * 4 + s;
        f32x4 v = {fv[s*4+0], fv[s*4+1], fv[s*4+2], fv[s*4+3]};
        *(f32x4*)&myfv[rloc * 64 + ((ce * 4 + rloc * 4) & 63)] = v;
    }
    // same-wave read-after-write (in-order per wave; no barrier)

    // ---- phase 4: z = fv + F*sbase; sigmoid; 2-shuffle reduce ----
    float ps = 0.f;
    #pragma unroll
    for (int n = 0; n < 4; ++n) {
        f32x4 fp = *(f32x4*)&myfv[r15 * 64 + ((n * 16 + g4 * 4 + r15 * 4) & 63)];
        float4 sb = *(const float4*)&sbase[hp * 128 + ch * 64 + n * 16 + g4 * 4];
        float sbv[4] = {sb.x, sb.y, sb.z, sb.w};
        #pragma unroll
        for (int reg = 0; reg < 4; ++reg) {
            float z = fp[reg] + acc[n][reg] * sbv[reg];
            ps += sigmoid_fast(z);
        }
    }
    // row total: sum across the 4 g4-groups holding this row (lane = r15+16*g4)
    ps += __shfl_xor(ps, 16, 64);
    ps += __shfl_xor(ps, 32, 64);
    if (g4 == 0) {
        (ch ? sums_hi : sums_lo)[row0 + xrow] = ps;   // 16-lane coalesced
    }
}

// Fused tail: grid 256 = one bh per block. T/R matvec (all 256 threads,
// p-split + LDS combine), then wave-per-row softmax for all 128 rows.
__global__ __launch_bounds__(256) void k_attn(
    const float* __restrict__ sums_lo, const float* __restrict__ sums_hi,
    const float* __restrict__ w_qk, const float* __restrict__ b_qk,
    float* __restrict__ out)
{
    __shared__ float skl[128], Tp[2][128], Rp[2][128], Tl[128], Rl[128];
    const int bh = blockIdx.x;
    const int t = threadIdx.x;

    if (t < 128) {
        int idx = 32768 + bh * 128 + t;
        skl[t] = sums_lo[idx] + sums_hi[idx];
    }
    __syncthreads();
    {
        int j = t & 127, ph = t >> 7;         // p-half 0/1
        const float4* wr = (const float4*)&w_qk[j * 128 + ph * 64];
        const float* sk2 = &skl[ph * 64];
        float a = 0.f, r = 0.f;
        #pragma unroll 8
        for (int p4 = 0; p4 < 16; ++p4) {
            float4 w4 = wr[p4];
            a += w4.x * sk2[p4 * 4 + 0] + w4.y * sk2[p4 * 4 + 1] +
                 w4.z * sk2[p4 * 4 + 2] + w4.w * sk2[p4 * 4 + 3];
            r += w4.x + w4.y + w4.z + w4.w;
        }
        Tp[ph][j] = a;
        Rp[ph][j] = r;
    }
    __syncthreads();
    if (t < 128) {
        Tl[t] = Tp[0][t] + Tp[1][t] + b_qk[t];
        Rl[t] = Rp[0][t] + Rp[1][t];
    }
    __syncthreads();

    const int lane = t & 63, w = t >> 6;
    #pragma unroll 8
    for (int it = 0; it < 32; ++it) {
        int row = bh * 128 + it * 4 + w;      // global q-row
        float sqv = sums_lo[row] + sums_hi[row];
        float2 r2 = *(const float2*)&Rl[lane * 2];
        float2 t2 = *(const float2*)&Tl[lane * 2];
        float l0 = __builtin_fmaf(sqv, r2.x, t2.x);
        float l1 = __builtin_fmaf(sqv, r2.y, t2.y);
        float m = fmaxf(l0, l1);
        #pragma unroll
        for (int s = 32; s >= 1; s >>= 1) m = fmaxf(m, __shfl_xor(m, s, 64));
        float e0 = hw_exp2((l0 - m) * LOG2E);
        float e1 = hw_exp2((l1 - m) * LOG2E);
        float sum = e0 + e1;
        #pragma unroll
        for (int w2 = 32; w2 >= 1; w2 >>= 1) sum += __shfl_xor(sum, w2, 64);
        float inv = fastrcp(sum);
        float2 o2 = {e0 * inv, e1 * inv};
        *(float2*)&out[row * 128 + lane * 2] = o2;
    }
}

extern "C" void kernel_launch(void* const* d_in, const int* in_sizes, int n_in,
                              void* d_out, int out_size, void* d_ws, size_t ws_size,
                              hipStream_t stream) {
    (void)in_sizes; (void)n_in; (void)out_size; (void)ws_size;
    const float* q      = (const float*)d_in[0];
    const float* k      = (const float*)d_in[1];
    // d_in[2] = scale (unused by reference forward)
    const float* gridv  = (const float*)d_in[3];
    const float* bw     = (const float*)d_in[4];
    const float* coef_q = (const float*)d_in[5];
    const float* coef_k = (const float*)d_in[6];
    const float* sbase  = (const float*)d_in[7];   // scale_base
    const float* ssp    = (const float*)d_in[8];   // scale_sp
    const float* w_qk   = (const float*)d_in[9];
    const float* b_qk   = (const float*)d_in[10];

    float* out  = (float*)d_out;
    float* ws      = (float*)d_ws;
    float* sums_lo = ws;                            // 65536
    float* sums_hi = ws + 65536;                    // 65536
    unsigned short* wbf = (unsigned short*)(ws + 131072);  // 16384 ushorts

    k_convert<<<64, 256, 0, stream>>>(bw, wbf);
    k_branch<<<1024, 512, 0, stream>>>(q, k, wbf, gridv, coef_q, coef_k,
                                       sbase, ssp, sums_lo, sums_hi);
    k_attn<<<256, 256, 0, stream>>>(sums_lo, sums_hi, w_qk, b_qk, out);
}

// Round 20
// 42.007 us; speedup vs baseline: 1.0783x; 1.0783x over previous
//
#include <hip/hip_runtime.h>
#include <hip/hip_bf16.h>

// Problem: B=16,H=16,P=128,D=128,NF=12
// rows per branch = B*H*P = 32768; total rows (q then k) = 65536.
//
// R20 = R18 (best known, 41.0 us) with the sin-dot coef reads converted
// from 192 ds_read_b32/wave to 48 ds_read_b128/wave:
//   coef staged in LDS as [d][12] with a 4-float skew every 8 rows
//   (addr = d*12 + (d>>3)*4) -> the 4 distinct d's per wave-instruction
//   (g4 groups) hit bank quads 0-3/4-7/8-11/12-15: conflict-free b128
//   broadcasts. 12 transient regs, nothing new lives across the loop
//   (R19's spill poison avoided), no new global loads (R19's other poison).
// k_attn: grid 256 (one bh per block; w_qk traffic halved) from R19.
//
// ws layout (floats): sums_lo [0,65536)  sums_hi [65536,131072)
//                     wbf: ushort[16384] at float offset 131072

typedef float          f32x4 __attribute__((ext_vector_type(4)));
typedef short          s16x8 __attribute__((ext_vector_type(8)));
typedef int            s32x4 __attribute__((ext_vector_type(4)));
typedef unsigned short u16x8 __attribute__((ext_vector_type(8)));

#define LOG2E   1.44269504f
#define NLOG2E -1.44269504f
#define INV2PI  0.15915494309189535f

static __device__ __forceinline__ float hw_exp2(float x) {   // 2^x
    float r;
    asm("v_exp_f32 %0, %1" : "=v"(r) : "v"(x));
    return r;
}
static __device__ __forceinline__ float hw_fract(float x) {
    float r;
    asm("v_fract_f32 %0, %1" : "=v"(r) : "v"(x));
    return r;
}
static __device__ __forceinline__ float hw_sin01(float f) {  // sin(2*pi*f)
    float r;
    asm("v_sin_f32 %0, %1" : "=v"(r) : "v"(f));
    return r;
}
static __device__ __forceinline__ float hw_cos01(float f) {  // cos(2*pi*f)
    float r;
    asm("v_cos_f32 %0, %1" : "=v"(r) : "v"(f));
    return r;
}
static __device__ __forceinline__ float fastrcp(float x) {
    return __builtin_amdgcn_rcpf(x);
}
static __device__ __forceinline__ unsigned int cvt_pk_bf16(float lo, float hi) {
    unsigned int r;
    asm("v_cvt_pk_bf16_f32 %0, %1, %2" : "=v"(r) : "v"(lo), "v"(hi));
    return r;
}
static __device__ __forceinline__ float sigmoid_fast(float z) {
    return fastrcp(1.f + hw_exp2(z * NLOG2E));
}
// XOR swizzle for [row][256B] bf16 LDS tiles read 16B/lane (measured-good)
static __device__ __forceinline__ int swz(int local) {
    return local ^ (((local >> 8) & 7) << 4);
}
// coef LDS address (floats): natural [d][12] + 4-float skew per 8 rows
static __device__ __forceinline__ int cfa(int d) {
    return d * 12 + ((d >> 3) << 2);
}

__global__ __launch_bounds__(256) void k_convert(const float* __restrict__ bw,
                                                 unsigned short* __restrict__ wbf) {
    int i = blockIdx.x * 256 + threadIdx.x;
    if (i < 128 * 128) {
        __hip_bfloat16 h = __float2bfloat16(bw[i]);
        unsigned short r;
        __builtin_memcpy(&r, &h, 2);
        wbf[i] = r;
    }
}

__global__ __launch_bounds__(512, 4) void k_branch(
    const float* __restrict__ q, const float* __restrict__ k,
    const unsigned short* __restrict__ wbf,   // W bf16 [d][e]
    const float* __restrict__ gridv,          // [12], == 1..12
    const float* __restrict__ coef_q, const float* __restrict__ coef_k,
    const float* __restrict__ sbase,          // scale_base (1,H,P,D)
    const float* __restrict__ ssp,            // scale_sp   (1,H,P,D)
    float* __restrict__ sums_lo, float* __restrict__ sums_hi)
{
    __shared__ char smem[32768 + 6400];
    // [0,32768): W bf16 swizzled; after barrier-2 the same region holds the
    // per-wave fv bounce ([16][64] f32, rotated). [32768,+6400): coef skewed.
    float* cfl = (float*)(smem + 32768);

    const int t = threadIdx.x;
    const int lane = t & 63, w = t >> 6;      // 8 waves
    const int wr = w >> 1;                    // row group 0..3
    const int ch = w & 1;                     // col half 0/1
    const int r15 = lane & 15, g4 = lane >> 4;
    const int row0 = blockIdx.x * 64;
    const bool is_q = row0 < 32768;
    const float* X = is_q ? q : k;
    const float* coef = is_q ? coef_q : coef_k;
    const int xrow0 = is_q ? row0 : row0 - 32768;
    const float g1 = gridv[0];                // == 1.0; freqs are g1*(1..12)
    const float grev = g1 * INV2PI;

    // ---- phase 1a: stage W bf16 (4 x 16B per thread, coalesced) ----
    #pragma unroll
    for (int it = 0; it < 4; ++it) {
        int c = it * 512 + t;                 // chunk 0..2047
        u16x8 v = *(const u16x8*)&wbf[c * 8];
        *(u16x8*)(smem + swz(c * 16)) = v;
    }
    // ---- phase 1b: stage coef, natural layout + skew ----
    #pragma unroll
    for (int it = 0; it < 3; ++it) {
        int e = it * 512 + t;                 // 0..1535 = d*12+u
        float v = coef[e];
        int d = e / 12, u = e - d * 12;       // compiler magic-mul
        cfl[cfa(d) + u] = v;
    }
    __syncthreads();

    // ---- phase 2: MFMA (swapped operands) with co-scheduled sin-dot ----
    const int xrow = wr * 16 + r15;           // this lane's x-row in block
    const float* xrowp = &X[(xrow0 + xrow) * 128];
    const int hp = (row0 + xrow) & 2047;
    const float* ssprow = &ssp[hp * 128];

    f32x4 acc[4];
    #pragma unroll
    for (int n = 0; n < 4; ++n) acc[n] = (f32x4){0.f, 0.f, 0.f, 0.f};
    float fv[16];                             // sin-dot*ssp for 2 s-slices

    #pragma unroll
    for (int s = 0; s < 4; ++s) {
        const float4* xp = (const float4*)&xrowp[s * 32 + g4 * 8];
        float4 x0 = xp[0], x1 = xp[1];
        float xsv[8] = {x0.x, x0.y, x0.z, x0.w, x1.x, x1.y, x1.z, x1.w};
        float sl[8];
        #pragma unroll
        for (int j = 0; j < 8; ++j) {
            float e = hw_exp2(xsv[j] * NLOG2E);          // e^-x
            sl[j] = xsv[j] * fastrcp(1.f + e);           // silu
        }
        s32x4 a4 = {(int)cvt_pk_bf16(sl[0], sl[1]), (int)cvt_pk_bf16(sl[2], sl[3]),
                    (int)cvt_pk_bf16(sl[4], sl[5]), (int)cvt_pk_bf16(sl[6], sl[7])};
        s16x8 af = __builtin_bit_cast(s16x8, a4);

        // sin-dot for this wave's ch-half (s-slices 2ch, 2ch+1) — interleaves
        // with the MFMA ds_reads/issue below (wave-uniform branch).
        if ((s >> 1) == ch) {
            const int s2 = s & 1;
            const float4* spp = (const float4*)&ssprow[s * 32 + g4 * 8];
            float4 sp0 = spp[0], sp1 = spp[1];
            float spv[8] = {sp0.x, sp0.y, sp0.z, sp0.w,
                            sp1.x, sp1.y, sp1.z, sp1.w};
            #pragma unroll
            for (int j = 0; j < 8; ++j) {
                int d = s * 32 + g4 * 8 + j;             // global col 0..127
                // 3 x ds_read_b128 broadcast, conflict-free (skewed layout)
                const f32x4* cb = (const f32x4*)&cfl[cfa(d)];
                f32x4 c0 = cb[0], c1 = cb[1], c2 = cb[2];
                float rev = hw_fract(grev * xsv[j]);
                float s1 = hw_sin01(rev);
                float cv = hw_cos01(rev);
                float t2 = cv + cv;
                float f = c0[0] * s1;
                float sprev = s1, scur;
                scur = __builtin_fmaf(t2, s1, -0.f);     // sin2
                f = __builtin_fmaf(c0[1], scur, f);
                float sn;
                sn = __builtin_fmaf(t2, scur, -sprev); f = __builtin_fmaf(c0[2], sn, f); sprev = scur; scur = sn;
                sn = __builtin_fmaf(t2, scur, -sprev); f = __builtin_fmaf(c0[3], sn, f); sprev = scur; scur = sn;
                sn = __builtin_fmaf(t2, scur, -sprev); f = __builtin_fmaf(c1[0], sn, f); sprev = scur; scur = sn;
                sn = __builtin_fmaf(t2, scur, -sprev); f = __builtin_fmaf(c1[1], sn, f); sprev = scur; scur = sn;
                sn = __builtin_fmaf(t2, scur, -sprev); f = __builtin_fmaf(c1[2], sn, f); sprev = scur; scur = sn;
                sn = __builtin_fmaf(t2, scur, -sprev); f = __builtin_fmaf(c1[3], sn, f); sprev = scur; scur = sn;
                sn = __builtin_fmaf(t2, scur, -sprev); f = __builtin_fmaf(c2[0], sn, f); sprev = scur; scur = sn;
                sn = __builtin_fmaf(t2, scur, -sprev); f = __builtin_fmaf(c2[1], sn, f); sprev = scur; scur = sn;
                sn = __builtin_fmaf(t2, scur, -sprev); f = __builtin_fmaf(c2[2], sn, f); sprev = scur; scur = sn;
                sn = __builtin_fmaf(t2, scur, -sprev); f = __builtin_fmaf(c2[3], sn, f);
                fv[s2 * 8 + j] = f * spv[j];
            }
        }

        #pragma unroll
        for (int n = 0; n < 4; ++n) {
            s16x8 bfw = *(const s16x8*)(smem + swz((ch * 64 + n * 16 + r15) * 256
                                                   + s * 64 + g4 * 16));
            // swapped: A = W-frag (M=d), B = silu-frag (N=x-row)
            acc[n] = __builtin_amdgcn_mfma_f32_16x16x32_bf16(bfw, af, acc[n], 0, 0, 0);
        }
    }
    __syncthreads();                          // all waves done with W region

    // ---- phase 3: fv bounce through dead-W overlay (wave-private, rotated)
    float* myfv = (float*)smem + w * 1024;    // [16][64] floats
    #pragma unroll
    for (int s2 = 0; s2 < 2; ++s2) {
        #pragma unroll
        for (int jb = 0; jb < 2; ++jb) {
            int dloc = s2 * 32 + g4 * 8 + jb * 4;
            f32x4 v = {fv[s2*8 + jb*4 + 0], fv[s2*8 + jb*4 + 1],
                       fv[s2*8 + jb*4 + 2], fv[s2*8 + jb*4 + 3]};
            *(f32x4*)&myfv[r15 * 64 + ((dloc + r15 * 4) & 63)] = v;
        }
    }
    // same-wave read-after-write (in-order per wave; no barrier)

    // ---- phase 4: z = fv + F*sbase; sigmoid; 2-shuffle reduce ----
    float ps = 0.f;
    #pragma unroll
    for (int n = 0; n < 4; ++n) {
        f32x4 fp = *(f32x4*)&myfv[r15 * 64 + ((n * 16 + g4 * 4 + r15 * 4) & 63)];
        float4 sb = *(const float4*)&sbase[hp * 128 + ch * 64 + n * 16 + g4 * 4];
        float sbv[4] = {sb.x, sb.y, sb.z, sb.w};
        #pragma unroll
        for (int reg = 0; reg < 4; ++reg) {
            float z = fp[reg] + acc[n][reg] * sbv[reg];
            ps += sigmoid_fast(z);
        }
    }
    // row total: sum across the 4 g4-groups holding this row (lane = r15+16*g4)
    ps += __shfl_xor(ps, 16, 64);
    ps += __shfl_xor(ps, 32, 64);
    if (g4 == 0) {
        (ch ? sums_hi : sums_lo)[row0 + xrow] = ps;   // 16-lane coalesced
    }
}

// Fused tail: grid 256 = one bh per block. T/R matvec (all 256 threads,
// p-split + LDS combine), then wave-per-row softmax for all 128 rows.
__global__ __launch_bounds__(256) void k_attn(
    const float* __restrict__ sums_lo, const float* __restrict__ sums_hi,
    const float* __restrict__ w_qk, const float* __restrict__ b_qk,
    float* __restrict__ out)
{
    __shared__ float skl[128], Tp[2][128], Rp[2][128], Tl[128], Rl[128];
    const int bh = blockIdx.x;
    const int t = threadIdx.x;

    if (t < 128) {
        int idx = 32768 + bh * 128 + t;
        skl[t] = sums_lo[idx] + sums_hi[idx];
    }
    __syncthreads();
    {
        int j = t & 127, ph = t >> 7;         // p-half 0/1
        const float4* wr = (const float4*)&w_qk[j * 128 + ph * 64];
        const float* sk2 = &skl[ph * 64];
        float a = 0.f, r = 0.f;
        #pragma unroll 8
        for (int p4 = 0; p4 < 16; ++p4) {
            float4 w4 = wr[p4];
            a += w4.x * sk2[p4 * 4 + 0] + w4.y * sk2[p4 * 4 + 1] +
                 w4.z * sk2[p4 * 4 + 2] + w4.w * sk2[p4 * 4 + 3];
            r += w4.x + w4.y + w4.z + w4.w;
        }
        Tp[ph][j] = a;
        Rp[ph][j] = r;
    }
    __syncthreads();
    if (t < 128) {
        Tl[t] = Tp[0][t] + Tp[1][t] + b_qk[t];
        Rl[t] = Rp[0][t] + Rp[1][t];
    }
    __syncthreads();

    const int lane = t & 63, w = t >> 6;
    #pragma unroll 8
    for (int it = 0; it < 32; ++it) {
        int row = bh * 128 + it * 4 + w;      // global q-row
        float sqv = sums_lo[row] + sums_hi[row];
        float2 r2 = *(const float2*)&Rl[lane * 2];
        float2 t2 = *(const float2*)&Tl[lane * 2];
        float l0 = __builtin_fmaf(sqv, r2.x, t2.x);
        float l1 = __builtin_fmaf(sqv, r2.y, t2.y);
        float m = fmaxf(l0, l1);
        #pragma unroll
        for (int s = 32; s >= 1; s >>= 1) m = fmaxf(m, __shfl_xor(m, s, 64));
        float e0 = hw_exp2((l0 - m) * LOG2E);
        float e1 = hw_exp2((l1 - m) * LOG2E);
        float sum = e0 + e1;
        #pragma unroll
        for (int w2 = 32; w2 >= 1; w2 >>= 1) sum += __shfl_xor(sum, w2, 64);
        float inv = fastrcp(sum);
        float2 o2 = {e0 * inv, e1 * inv};
        *(float2*)&out[row * 128 + lane * 2] = o2;
    }
}

extern "C" void kernel_launch(void* const* d_in, const int* in_sizes, int n_in,
                              void* d_out, int out_size, void* d_ws, size_t ws_size,
                              hipStream_t stream) {
    (void)in_sizes; (void)n_in; (void)out_size; (void)ws_size;
    const float* q      = (const float*)d_in[0];
    const float* k      = (const float*)d_in[1];
    // d_in[2] = scale (unused by reference forward)
    const float* gridv  = (const float*)d_in[3];
    const float* bw     = (const float*)d_in[4];
    const float* coef_q = (const float*)d_in[5];
    const float* coef_k = (const float*)d_in[6];
    const float* sbase  = (const float*)d_in[7];   // scale_base
    const float* ssp    = (const float*)d_in[8];   // scale_sp
    const float* w_qk   = (const float*)d_in[9];
    const float* b_qk   = (const float*)d_in[10];

    float* out  = (float*)d_out;
    float* ws      = (float*)d_ws;
    float* sums_lo = ws;                            // 65536
    float* sums_hi = ws + 65536;                    // 65536
    unsigned short* wbf = (unsigned short*)(ws + 131072);  // 16384 ushorts

    k_convert<<<64, 256, 0, stream>>>(bw, wbf);
    k_branch<<<1024, 512, 0, stream>>>(q, k, wbf, gridv, coef_q, coef_k,
                                       sbase, ssp, sums_lo, sums_hi);
    k_attn<<<256, 256, 0, stream>>>(sums_lo, sums_hi, w_qk, b_qk, out);
}

// Round 21
// 38.360 us; speedup vs baseline: 1.1808x; 1.0951x over previous
//
#include <hip/hip_runtime.h>
#include <hip/hip_bf16.h>

// Problem: B=16,H=16,P=128,D=128,NF=12
// rows per branch = B*H*P = 32768; total rows (q then k) = 65536.
//
// R21 = R18 (best known, 41.0us) + three proven/derisked trims:
//  1. Chebyshev sin-dot on packed f32 (v_pk_fma_f32/v_pk_mul_f32): element
//     PAIRS, 2x issue rate on the largest VALU block; coef pair fetched by
//     ds_read_b64 from R18's unchanged cfl[u*128+d] layout (adjacent d).
//     Same arithmetic, same rounding -> absmax unchanged.
//  2. k_convert deleted: W f32->bf16 converted inline in phase 1a (R16's
//     exact staging code). One fewer kernel launch + gap.
//  3. k_attn grid 256 (one bh per block; T/R once per bh) per R19/R20.
// k_branch phases otherwise BYTE-IDENTICAL to R18 (6 structural nulls ->
// no more phase restructuring; if >=41 us, plateau is declared).
//
// ws layout (floats): sums_lo [0,65536)  sums_hi [65536,131072)

typedef float          f32x4 __attribute__((ext_vector_type(4)));
typedef float          f32x2 __attribute__((ext_vector_type(2)));
typedef short          s16x8 __attribute__((ext_vector_type(8)));
typedef int            s32x4 __attribute__((ext_vector_type(4)));
typedef unsigned int   u32x4 __attribute__((ext_vector_type(4)));

#define LOG2E   1.44269504f
#define NLOG2E -1.44269504f
#define INV2PI  0.15915494309189535f

static __device__ __forceinline__ float hw_exp2(float x) {   // 2^x
    float r;
    asm("v_exp_f32 %0, %1" : "=v"(r) : "v"(x));
    return r;
}
static __device__ __forceinline__ float hw_fract(float x) {
    float r;
    asm("v_fract_f32 %0, %1" : "=v"(r) : "v"(x));
    return r;
}
static __device__ __forceinline__ float hw_sin01(float f) {  // sin(2*pi*f)
    float r;
    asm("v_sin_f32 %0, %1" : "=v"(r) : "v"(f));
    return r;
}
static __device__ __forceinline__ float hw_cos01(float f) {  // cos(2*pi*f)
    float r;
    asm("v_cos_f32 %0, %1" : "=v"(r) : "v"(f));
    return r;
}
static __device__ __forceinline__ float fastrcp(float x) {
    return __builtin_amdgcn_rcpf(x);
}
static __device__ __forceinline__ unsigned int cvt_pk_bf16(float lo, float hi) {
    unsigned int r;
    asm("v_cvt_pk_bf16_f32 %0, %1, %2" : "=v"(r) : "v"(lo), "v"(hi));
    return r;
}
static __device__ __forceinline__ float sigmoid_fast(float z) {
    return fastrcp(1.f + hw_exp2(z * NLOG2E));
}
// packed f32 ops (VOP3P, 2 elements per lane-instruction)
static __device__ __forceinline__ f32x2 pk_mul(f32x2 a, f32x2 b) {
    f32x2 d;
    asm("v_pk_mul_f32 %0, %1, %2" : "=v"(d) : "v"(a), "v"(b));
    return d;
}
static __device__ __forceinline__ f32x2 pk_fma(f32x2 a, f32x2 b, f32x2 c) {
    f32x2 d;
    asm("v_pk_fma_f32 %0, %1, %2, %3" : "=v"(d) : "v"(a), "v"(b), "v"(c));
    return d;
}
static __device__ __forceinline__ f32x2 pk_fma_nc(f32x2 a, f32x2 b, f32x2 c) {
    f32x2 d;   // a*b - c
    asm("v_pk_fma_f32 %0, %1, %2, %3 neg_lo:[0,0,1] neg_hi:[0,0,1]"
        : "=v"(d) : "v"(a), "v"(b), "v"(c));
    return d;
}
// XOR swizzle for [row][256B] bf16 LDS tiles read 16B/lane (measured-good)
static __device__ __forceinline__ int swz(int local) {
    return local ^ (((local >> 8) & 7) << 4);
}

__global__ __launch_bounds__(512, 4) void k_branch(
    const float* __restrict__ q, const float* __restrict__ k,
    const float* __restrict__ bw,             // base_weight f32 [d][e]
    const float* __restrict__ gridv,          // [12], == 1..12
    const float* __restrict__ coef_q, const float* __restrict__ coef_k,
    const float* __restrict__ sbase,          // scale_base (1,H,P,D)
    const float* __restrict__ ssp,            // scale_sp   (1,H,P,D)
    float* __restrict__ sums_lo, float* __restrict__ sums_hi)
{
    __shared__ char smem[32768 + 6144];
    // [0,32768): W bf16 swizzled; after barrier-2 the same region holds the
    // per-wave fv bounce ([16][64] f32, rotated). [32768,+6144): coef^T [12][128].
    float* cfl = (float*)(smem + 32768);

    const int t = threadIdx.x;
    const int lane = t & 63, w = t >> 6;      // 8 waves
    const int wr = w >> 1;                    // row group 0..3
    const int ch = w & 1;                     // col half 0/1
    const int r15 = lane & 15, g4 = lane >> 4;
    const int row0 = blockIdx.x * 64;
    const bool is_q = row0 < 32768;
    const float* X = is_q ? q : k;
    const float* coef = is_q ? coef_q : coef_k;
    const int xrow0 = is_q ? row0 : row0 - 32768;
    const float g1 = gridv[0];                // == 1.0; freqs are g1*(1..12)
    const float grev = g1 * INV2PI;

    // ---- phase 1a: stage W, f32 -> bf16 via cvt_pk (4 chunks/thread) ----
    #pragma unroll
    for (int it = 0; it < 4; ++it) {
        int c = it * 512 + t;                 // chunk 0..2047 (8 bf16 = 16B LDS)
        const float4* wp = (const float4*)&bw[(c >> 4) * 128 + (c & 15) * 8];
        float4 w0 = wp[0], w1 = wp[1];
        u32x4 v = {cvt_pk_bf16(w0.x, w0.y), cvt_pk_bf16(w0.z, w0.w),
                   cvt_pk_bf16(w1.x, w1.y), cvt_pk_bf16(w1.z, w1.w)};
        *(u32x4*)(smem + swz(c * 16)) = v;
    }
    // ---- phase 1b: stage coef transposed: cfl[u*128 + d] ----
    #pragma unroll
    for (int it = 0; it < 3; ++it) {
        int e = it * 512 + t;                 // 0..1535 = d*12+u
        float v = coef[e];
        int d = e / 12, u = e - d * 12;       // compiler magic-mul
        cfl[u * 128 + d] = v;
    }
    __syncthreads();

    // ---- phase 2: MFMA (swapped operands) with co-scheduled sin-dot ----
    const int xrow = wr * 16 + r15;           // this lane's x-row in block
    const float* xrowp = &X[(xrow0 + xrow) * 128];
    const int hp = (row0 + xrow) & 2047;
    const float* ssprow = &ssp[hp * 128];

    f32x4 acc[4];
    #pragma unroll
    for (int n = 0; n < 4; ++n) acc[n] = (f32x4){0.f, 0.f, 0.f, 0.f};
    float fv[16];                             // sin-dot*ssp for 2 s-slices

    #pragma unroll
    for (int s = 0; s < 4; ++s) {
        const float4* xp = (const float4*)&xrowp[s * 32 + g4 * 8];
        float4 x0 = xp[0], x1 = xp[1];
        float xsv[8] = {x0.x, x0.y, x0.z, x0.w, x1.x, x1.y, x1.z, x1.w};
        float sl[8];
        #pragma unroll
        for (int j = 0; j < 8; ++j) {
            float e = hw_exp2(xsv[j] * NLOG2E);          // e^-x
            sl[j] = xsv[j] * fastrcp(1.f + e);           // silu
        }
        s32x4 a4 = {(int)cvt_pk_bf16(sl[0], sl[1]), (int)cvt_pk_bf16(sl[2], sl[3]),
                    (int)cvt_pk_bf16(sl[4], sl[5]), (int)cvt_pk_bf16(sl[6], sl[7])};
        s16x8 af = __builtin_bit_cast(s16x8, a4);

        // sin-dot for this wave's ch-half (s-slices 2ch, 2ch+1), element
        // PAIRS on the packed-f32 pipe; coef pairs via ds_read_b64.
        if ((s >> 1) == ch) {
            const int s2 = s & 1;
            const float4* spp = (const float4*)&ssprow[s * 32 + g4 * 8];
            float4 sp0 = spp[0], sp1 = spp[1];
            float spv[8] = {sp0.x, sp0.y, sp0.z, sp0.w,
                            sp1.x, sp1.y, sp1.z, sp1.w};
            #pragma unroll
            for (int j2 = 0; j2 < 4; ++j2) {
                int d = s * 32 + g4 * 8 + j2 * 2;        // even: b64-aligned
                float xa = xsv[j2 * 2], xb = xsv[j2 * 2 + 1];
                float ra = hw_fract(grev * xa), rb = hw_fract(grev * xb);
                float sa = hw_sin01(ra), sb = hw_sin01(rb);
                float ca = hw_cos01(ra), cb = hw_cos01(rb);
                f32x2 t2p = {ca + ca, cb + cb};
                f32x2 scur = {sa, sb};
                f32x2 sprev = scur;
                f32x2 f2 = pk_mul(*(const f32x2*)&cfl[d], scur);        // u=0
                scur = pk_mul(t2p, scur);                               // sin2
                f2 = pk_fma(*(const f32x2*)&cfl[128 + d], scur, f2);    // u=1
                #pragma unroll
                for (int u = 2; u < 12; ++u) {
                    f32x2 sn = pk_fma_nc(t2p, scur, sprev);             // recur
                    f2 = pk_fma(*(const f32x2*)&cfl[u * 128 + d], sn, f2);
                    sprev = scur; scur = sn;
                }
                f32x2 sp2 = {spv[j2 * 2], spv[j2 * 2 + 1]};
                f32x2 r = pk_mul(f2, sp2);
                fv[s2 * 8 + j2 * 2]     = r[0];
                fv[s2 * 8 + j2 * 2 + 1] = r[1];
            }
        }

        #pragma unroll
        for (int n = 0; n < 4; ++n) {
            s16x8 bfw = *(const s16x8*)(smem + swz((ch * 64 + n * 16 + r15) * 256
                                                   + s * 64 + g4 * 16));
            // swapped: A = W-frag (M=d), B = silu-frag (N=x-row)
            acc[n] = __builtin_amdgcn_mfma_f32_16x16x32_bf16(bfw, af, acc[n], 0, 0, 0);
        }
    }
    __syncthreads();                          // all waves done with W region

    // ---- phase 3: fv bounce through dead-W overlay (wave-private, rotated)
    float* myfv = (float*)smem + w * 1024;    // [16][64] floats
    #pragma unroll
    for (int s2 = 0; s2 < 2; ++s2) {
        #pragma unroll
        for (int jb = 0; jb < 2; ++jb) {
            int dloc = s2 * 32 + g4 * 8 + jb * 4;
            f32x4 v = {fv[s2*8 + jb*4 + 0], fv[s2*8 + jb*4 + 1],
                       fv[s2*8 + jb*4 + 2], fv[s2*8 + jb*4 + 3]};
            *(f32x4*)&myfv[r15 * 64 + ((dloc + r15 * 4) & 63)] = v;
        }
    }
    // same-wave read-after-write (in-order per wave; no barrier)

    // ---- phase 4: z = fv + F*sbase; sigmoid; 2-shuffle reduce ----
    float ps = 0.f;
    #pragma unroll
    for (int n = 0; n < 4; ++n) {
        f32x4 fp = *(f32x4*)&myfv[r15 * 64 + ((n * 16 + g4 * 4 + r15 * 4) & 63)];
        float4 sb = *(const float4*)&sbase[hp * 128 + ch * 64 + n * 16 + g4 * 4];
        float sbv[4] = {sb.x, sb.y, sb.z, sb.w};
        #pragma unroll
        for (int reg = 0; reg < 4; ++reg) {
            float z = fp[reg] + acc[n][reg] * sbv[reg];
            ps += sigmoid_fast(z);
        }
    }
    // row total: sum across the 4 g4-groups holding this row (lane = r15+16*g4)
    ps += __shfl_xor(ps, 16, 64);
    ps += __shfl_xor(ps, 32, 64);
    if (g4 == 0) {
        (ch ? sums_hi : sums_lo)[row0 + xrow] = ps;   // 16-lane coalesced
    }
}

// Fused tail: grid 256 = one bh per block. T/R matvec (all 256 threads,
// p-split + LDS combine), then wave-per-row softmax for all 128 rows.
__global__ __launch_bounds__(256) void k_attn(
    const float* __restrict__ sums_lo, const float* __restrict__ sums_hi,
    const float* __restrict__ w_qk, const float* __restrict__ b_qk,
    float* __restrict__ out)
{
    __shared__ float skl[128], Tp[2][128], Rp[2][128], Tl[128], Rl[128];
    const int bh = blockIdx.x;
    const int t = threadIdx.x;

    if (t < 128) {
        int idx = 32768 + bh * 128 + t;
        skl[t] = sums_lo[idx] + sums_hi[idx];
    }
    __syncthreads();
    {
        int j = t & 127, ph = t >> 7;         // p-half 0/1
        const float4* wr = (const float4*)&w_qk[j * 128 + ph * 64];
        const float* sk2 = &skl[ph * 64];
        float a = 0.f, r = 0.f;
        #pragma unroll 8
        for (int p4 = 0; p4 < 16; ++p4) {
            float4 w4 = wr[p4];
            a += w4.x * sk2[p4 * 4 + 0] + w4.y * sk2[p4 * 4 + 1] +
                 w4.z * sk2[p4 * 4 + 2] + w4.w * sk2[p4 * 4 + 3];
            r += w4.x + w4.y + w4.z + w4.w;
        }
        Tp[ph][j] = a;
        Rp[ph][j] = r;
    }
    __syncthreads();
    if (t < 128) {
        Tl[t] = Tp[0][t] + Tp[1][t] + b_qk[t];
        Rl[t] = Rp[0][t] + Rp[1][t];
    }
    __syncthreads();

    const int lane = t & 63, w = t >> 6;
    #pragma unroll 8
    for (int it = 0; it < 32; ++it) {
        int row = bh * 128 + it * 4 + w;      // global q-row
        float sqv = sums_lo[row] + sums_hi[row];
        float2 r2 = *(const float2*)&Rl[lane * 2];
        float2 t2 = *(const float2*)&Tl[lane * 2];
        float l0 = __builtin_fmaf(sqv, r2.x, t2.x);
        float l1 = __builtin_fmaf(sqv, r2.y, t2.y);
        float m = fmaxf(l0, l1);
        #pragma unroll
        for (int s = 32; s >= 1; s >>= 1) m = fmaxf(m, __shfl_xor(m, s, 64));
        float e0 = hw_exp2((l0 - m) * LOG2E);
        float e1 = hw_exp2((l1 - m) * LOG2E);
        float sum = e0 + e1;
        #pragma unroll
        for (int w2 = 32; w2 >= 1; w2 >>= 1) sum += __shfl_xor(sum, w2, 64);
        float inv = fastrcp(sum);
        float2 o2 = {e0 * inv, e1 * inv};
        *(float2*)&out[row * 128 + lane * 2] = o2;
    }
}

extern "C" void kernel_launch(void* const* d_in, const int* in_sizes, int n_in,
                              void* d_out, int out_size, void* d_ws, size_t ws_size,
                              hipStream_t stream) {
    (void)in_sizes; (void)n_in; (void)out_size; (void)ws_size;
    const float* q      = (const float*)d_in[0];
    const float* k      = (const float*)d_in[1];
    // d_in[2] = scale (unused by reference forward)
    const float* gridv  = (const float*)d_in[3];
    const float* bw     = (const float*)d_in[4];
    const float* coef_q = (const float*)d_in[5];
    const float* coef_k = (const float*)d_in[6];
    const float* sbase  = (const float*)d_in[7];   // scale_base
    const float* ssp    = (const float*)d_in[8];   // scale_sp
    const float* w_qk   = (const float*)d_in[9];
    const float* b_qk   = (const float*)d_in[10];

    float* out  = (float*)d_out;
    float* ws      = (float*)d_ws;
    float* sums_lo = ws;                            // 65536
    float* sums_hi = ws + 65536;                    // 65536

    k_branch<<<1024, 512, 0, stream>>>(q, k, bw, gridv, coef_q, coef_k,
                                       sbase, ssp, sums_lo, sums_hi);
    k_attn<<<256, 256, 0, stream>>>(sums_lo, sums_hi, w_qk, b_qk, out);
}